// Round 1
// baseline (3173.326 us; speedup 1.0000x reference)
//
#include <hip/hip_runtime.h>
#include <cstdint>
#include <cstddef>

// ---------------------------------------------------------------------------
// SelfAttentionTransformer on MI355X (gfx950).
// L=4, D=1024, H=8, HS=128, T=1000, DFF=4096, B=8.
// Strategy: bf16 MFMA (16x16x32) for all GEMM-shaped work, fp32 residual/LN.
// ---------------------------------------------------------------------------

typedef unsigned short u16;
typedef unsigned int u32;
typedef __attribute__((ext_vector_type(8))) short s16x8;   // 8 bf16 raw bits
typedef __attribute__((ext_vector_type(4))) float f32x4;

#define DEV static __device__ __forceinline__

DEV float bf2f(u16 u) { union { u32 u; float f; } v; v.u = ((u32)u) << 16; return v.f; }
DEV u16 f2bf(float f) {
  union { float f; u32 u; } v; v.f = f;
  return (u16)((v.u + 0x7fffu + ((v.u >> 16) & 1u)) >> 16);   // RNE
}

// Inline-asm MFMA: avoids builtin signature ambiguity; operands force VGPRs.
#define MFMA(acc_, a_, b_) \
  asm volatile("v_mfma_f32_16x16x32_bf16 %0, %1, %2, %0" : "+v"(acc_) : "v"(a_), "v"(b_))

static constexpr int T_ = 1000, D_ = 1024, H_ = 8, HS_ = 128, B_ = 8;
static constexpr int BT_ = B_ * T_;   // 8000

// ---------------------------------------------------------------------------
// RoPE cos/sin table: tab[t*64 + i], theta_i = 10000^(-i/64), ang = t*theta.
// ---------------------------------------------------------------------------
__global__ void tab_kernel(float* __restrict__ ct, float* __restrict__ st) {
  const int id = blockIdx.x * 256 + threadIdx.x;   // 64000 = 1000*64
  const int i = id & 63, t = id >> 6;
  const float theta = powf(10000.f, -(float)i * (1.f / 64.f));
  const float ang = (float)t * theta;
  ct[id] = cosf(ang);
  st[id] = sinf(ang);
}

// f32 -> bf16 elementwise (n % 4 == 0)
__global__ void convert_kernel(const float* __restrict__ in, u16* __restrict__ out, int n) {
  const int i = (blockIdx.x * 256 + threadIdx.x) * 4;
  if (i < n) {
    const float4 v = *(const float4*)(in + i);
    uint2 pk;
    pk.x = (u32)f2bf(v.x) | ((u32)f2bf(v.y) << 16);
    pk.y = (u32)f2bf(v.z) | ((u32)f2bf(v.w) << 16);
    *(uint2*)(out + i) = pk;
  }
}

// ---------------------------------------------------------------------------
// Generic bf16 MFMA GEMM.  C[m,n] = sum_k A[m,k]*B(n,k)  (+bias, +gelu).
//  BKM=false: B is NT (n-major, k-contiguous: B[n*ldb+k]).
//  BKM=true : B is k-major (B[k*ldb+n]); staged to LDS with transpose.
//  BIAS: 0 none, 1 per-row (bias[m]), 2 per-col (bias[n]).
// 128x128 tile, BK=32, 4 waves (2x2), each wave 64x64 = 4x4 MFMA frags.
// ---------------------------------------------------------------------------
template <int BIAS, bool BKM, bool ACT, bool OUTBF>
__global__ __launch_bounds__(256) void gemm_kernel(
    const u16* __restrict__ A, const u16* __restrict__ B, void* __restrict__ Cv,
    const float* __restrict__ bias, int M, int N, int K, int lda, int ldb, int ldc,
    long sA, long sB, long sC) {
  __shared__ alignas(16) u16 As[128][40];
  __shared__ alignas(16) u16 Bs[128][40];
  const int z = blockIdx.z;
  A += (size_t)z * (size_t)sA;
  B += (size_t)z * (size_t)sB;
  const int m0 = blockIdx.y * 128, n0 = blockIdx.x * 128;
  const int tid = threadIdx.x;
  const int wid = tid >> 6, lane = tid & 63;
  const int wr = wid >> 1, wc = wid & 1;
  const int l15 = lane & 15, l4 = lane >> 4;
  f32x4 acc[4][4] = {};
  const int KT = (K + 31) >> 5;
  for (int kt = 0; kt < KT; ++kt) {
    const int kbase = kt << 5;
    {  // stage A tile: rows m0..m0+127, k window [kbase, kbase+32)
      const int row = tid >> 1, koff = (tid & 1) << 4;
      const int gm = m0 + row;
#pragma unroll
      for (int v = 0; v < 2; ++v) {
        const int k0 = kbase + koff + v * 8;
        s16x8 val = {};
        if (gm < M) {
          if (k0 + 8 <= K) val = *(const s16x8*)(A + (size_t)gm * lda + k0);
          else {
#pragma unroll
            for (int j = 0; j < 8; ++j) { const int kk = k0 + j; if (kk < K) val[j] = (short)A[(size_t)gm * lda + kk]; }
          }
        }
        *(s16x8*)&As[row][koff + v * 8] = val;
      }
    }
    if (!BKM) {  // stage B tile, NT layout
      const int row = tid >> 1, koff = (tid & 1) << 4;
      const int gn = n0 + row;
#pragma unroll
      for (int v = 0; v < 2; ++v) {
        const int k0 = kbase + koff + v * 8;
        s16x8 val = {};
        if (gn < N) {
          if (k0 + 8 <= K) val = *(const s16x8*)(B + (size_t)gn * ldb + k0);
          else {
#pragma unroll
            for (int j = 0; j < 8; ++j) { const int kk = k0 + j; if (kk < K) val[j] = (short)B[(size_t)gn * ldb + kk]; }
          }
        }
        *(s16x8*)&Bs[row][koff + v * 8] = val;
      }
    } else {  // stage B tile, k-major: coalesced read rows of n, transpose into Bs[n][k]
      const int kk = tid >> 3, nof = (tid & 7) << 4;
      const int gk = kbase + kk;
#pragma unroll
      for (int v = 0; v < 2; ++v) {
        const int nb = nof + v * 8;
        const int gn = n0 + nb;
        s16x8 val = {};
        if (gk < K) {
          if (gn + 8 <= N) val = *(const s16x8*)(B + (size_t)gk * ldb + gn);
          else {
#pragma unroll
            for (int j = 0; j < 8; ++j) { if (gn + j < N) val[j] = (short)B[(size_t)gk * ldb + gn + j]; }
          }
        }
#pragma unroll
        for (int j = 0; j < 8; ++j) Bs[nb + j][kk] = (u16)val[j];
      }
    }
    __syncthreads();
    s16x8 af[4], bfr[4];
#pragma unroll
    for (int i = 0; i < 4; ++i) af[i] = *(const s16x8*)&As[wr * 64 + i * 16 + l15][l4 * 8];
#pragma unroll
    for (int i = 0; i < 4; ++i) bfr[i] = *(const s16x8*)&Bs[wc * 64 + i * 16 + l15][l4 * 8];
#pragma unroll
    for (int mi = 0; mi < 4; ++mi)
#pragma unroll
      for (int ni = 0; ni < 4; ++ni) MFMA(acc[mi][ni], af[mi], bfr[ni]);
    __syncthreads();
  }
  // MFMA->VALU hazard fence for the last-written accumulators
  asm volatile("s_nop 7\n\ts_nop 7"
               : "+v"(acc[3][0]), "+v"(acc[3][1]), "+v"(acc[3][2]), "+v"(acc[3][3]));
#pragma unroll
  for (int mi = 0; mi < 4; ++mi) {
#pragma unroll
    for (int ni = 0; ni < 4; ++ni) {
      const int colg = n0 + wc * 64 + ni * 16 + l15;
#pragma unroll
      for (int r = 0; r < 4; ++r) {
        const int rowg = m0 + wr * 64 + mi * 16 + l4 * 4 + r;
        if (rowg < M && colg < N) {
          float v = acc[mi][ni][r];
          if (BIAS == 1) v += bias[rowg];
          if (BIAS == 2) v += bias[colg];
          if (ACT) v = 0.5f * v * (1.0f + erff(v * 0.70710678118654752f));  // exact gelu
          const size_t idx = (size_t)z * (size_t)sC + (size_t)rowg * ldc + colg;
          if (OUTBF) ((u16*)Cv)[idx] = f2bf(v);
          else       ((float*)Cv)[idx] = v;
        }
      }
    }
  }
}

// ---------------------------------------------------------------------------
// RoPE in place on a bf16 (B,T,D) buffer. Pairs (2i,2i+1) within each head.
// ---------------------------------------------------------------------------
__global__ __launch_bounds__(256) void rope_kernel(u16* __restrict__ X,
                                                   const float* __restrict__ ct,
                                                   const float* __restrict__ st) {
  const int id = blockIdx.x * 256 + threadIdx.x;  // 8*1000*8*64 = 4,096,000
  const int i = id & 63;
  const int h = (id >> 6) & 7;
  const int bt = id >> 9;          // b*1000 + t  (== row index in (B*T, D))
  const int t = bt % 1000;
  const size_t base = (size_t)bt * D_ + h * HS_ + i * 2;
  u32* p = (u32*)(X + base);
  const u32 w = *p;
  const float xr = bf2f((u16)(w & 0xffffu));
  const float xi = bf2f((u16)(w >> 16));
  const float c = ct[t * 64 + i], s = st[t * 64 + i];
  const float outr = xr * c - xi * s;
  const float outi = xr * s + xi * c;
  *p = (u32)f2bf(outr) | ((u32)f2bf(outi) << 16);
}

// ---------------------------------------------------------------------------
// Flash attention, non-causal. One block = one (b,h) x 64 q-rows; 4 waves,
// each wave owns 16 q-rows. K-tiles of 64 keys. Online softmax.
// ---------------------------------------------------------------------------
__global__ __launch_bounds__(256) void attn_kernel(const u16* __restrict__ Q,
                                                   const u16* __restrict__ Kr,
                                                   const u16* __restrict__ V,
                                                   float* __restrict__ Y) {
  __shared__ alignas(16) u16 Ks[64][136];     // [key][hs], +8 pad
  __shared__ alignas(16) u16 Vt[128][72];     // [hs][key], +8 pad (transposed)
  __shared__ alignas(16) u16 Ps[4][16][72];   // per-wave P (16 q x 64 k), +8 pad
  const int qt = blockIdx.x;                  // 16 q-tiles of 64
  const int bh = blockIdx.y;                  // 64 = B*H
  const int b = bh >> 3, h = bh & 7;
  const int tid = threadIdx.x;
  const int w = tid >> 6, lane = tid & 63;
  const int l15 = lane & 15, l4 = lane >> 4;
  const size_t headoff = (size_t)b * T_ * D_ + h * HS_;
  // Q fragments (A-operand), held across the k-loop
  const int qrow = qt * 64 + w * 16 + l15;
  s16x8 aq[4];
#pragma unroll
  for (int c = 0; c < 4; ++c) {
    s16x8 v = {};
    if (qrow < T_) v = *(const s16x8*)(Q + headoff + (size_t)qrow * D_ + c * 32 + l4 * 8);
    aq[c] = v;
  }
  f32x4 acc[8] = {};
  float m_run[4], l_run[4];
#pragma unroll
  for (int r = 0; r < 4; ++r) { m_run[r] = -1e30f; l_run[r] = 0.f; }
  const float SCALE = 0.08838834764831845f;  // 1/sqrt(128)
  for (int kt = 0; kt < 16; ++kt) {
    {  // stage K tile (row-major) and V tile (transposed)
      const int r = tid >> 2, c0 = (tid & 3) << 5;
      const int kk = kt * 64 + r;
#pragma unroll
      for (int v = 0; v < 4; ++v) {
        s16x8 val = {};
        if (kk < T_) val = *(const s16x8*)(Kr + headoff + (size_t)kk * D_ + c0 + v * 8);
        *(s16x8*)&Ks[r][c0 + v * 8] = val;
      }
#pragma unroll
      for (int v = 0; v < 4; ++v) {
        s16x8 val = {};
        if (kk < T_) val = *(const s16x8*)(V + headoff + (size_t)kk * D_ + c0 + v * 8);
#pragma unroll
        for (int j = 0; j < 8; ++j) Vt[c0 + v * 8 + j][r] = (u16)val[j];
      }
    }
    __syncthreads();
    // S = Q K^T for this wave's 16 q-rows x 64 keys
    f32x4 sacc[4] = {};
#pragma unroll
    for (int c = 0; c < 4; ++c)
#pragma unroll
      for (int f = 0; f < 4; ++f) {
        s16x8 bk = *(const s16x8*)&Ks[f * 16 + l15][c * 32 + l4 * 8];
        MFMA(sacc[f], aq[c], bk);
      }
    asm volatile("s_nop 7\n\ts_nop 7"
                 : "+v"(sacc[0]), "+v"(sacc[1]), "+v"(sacc[2]), "+v"(sacc[3]));
    float sv[4][4];
#pragma unroll
    for (int f = 0; f < 4; ++f) {
      const int key = kt * 64 + f * 16 + l15;
#pragma unroll
      for (int r = 0; r < 4; ++r) sv[f][r] = (key < T_) ? sacc[f][r] * SCALE : -1e30f;
    }
#pragma unroll
    for (int r = 0; r < 4; ++r) {
      float mx = fmaxf(fmaxf(sv[0][r], sv[1][r]), fmaxf(sv[2][r], sv[3][r]));
#pragma unroll
      for (int off = 8; off >= 1; off >>= 1) mx = fmaxf(mx, __shfl_xor(mx, off));
      const float mn = fmaxf(m_run[r], mx);
      const float corr = __expf(m_run[r] - mn);
      m_run[r] = mn;
      float rs = 0.f;
#pragma unroll
      for (int f = 0; f < 4; ++f) {
        const float p = __expf(sv[f][r] - mn);
        rs += p;
        Ps[w][l4 * 4 + r][f * 16 + l15] = f2bf(p);
      }
#pragma unroll
      for (int off = 8; off >= 1; off >>= 1) rs += __shfl_xor(rs, off);
      l_run[r] = l_run[r] * corr + rs;
#pragma unroll
      for (int n = 0; n < 8; ++n) acc[n][r] *= corr;
    }
    __syncthreads();  // Ps visible; also keeps waves lockstep
    // O += P V
#pragma unroll
    for (int c2 = 0; c2 < 2; ++c2) {
      const s16x8 pa = *(const s16x8*)&Ps[w][l15][c2 * 32 + l4 * 8];
#pragma unroll
      for (int n = 0; n < 8; ++n) {
        const s16x8 vb = *(const s16x8*)&Vt[n * 16 + l15][c2 * 32 + l4 * 8];
        MFMA(acc[n], pa, vb);
      }
    }
    __syncthreads();  // protect Ks/Vt before next staging
  }
  asm volatile("s_nop 7\n\ts_nop 7"
               : "+v"(acc[4]), "+v"(acc[5]), "+v"(acc[6]), "+v"(acc[7]));
#pragma unroll
  for (int n = 0; n < 8; ++n)
#pragma unroll
    for (int r = 0; r < 4; ++r) {
      const int q = qt * 64 + w * 16 + l4 * 4 + r;
      if (q < T_) Y[headoff + (size_t)q * D_ + n * 16 + l15] = acc[n][r] / l_run[r];
    }
}

// ---------------------------------------------------------------------------
// src = LN(src + add) * g + b  (fp32 master), also writes bf16 mirror.
// One block per row (D=1024), 256 threads x 4 elems.
// ---------------------------------------------------------------------------
__global__ __launch_bounds__(256) void addln_kernel(float* __restrict__ src,
                                                    const float* __restrict__ add,
                                                    const float* __restrict__ g,
                                                    const float* __restrict__ bb,
                                                    u16* __restrict__ outb) {
  const int row = blockIdx.x;
  const int tid = threadIdx.x;
  float* s = src + (size_t)row * D_;
  const float* a = add + (size_t)row * D_;
  float x[4];
  float sum = 0.f, sq = 0.f;
#pragma unroll
  for (int i = 0; i < 4; ++i) {
    const int d = tid + i * 256;
    const float v = s[d] + a[d];
    x[i] = v; sum += v; sq += v * v;
  }
#pragma unroll
  for (int off = 32; off >= 1; off >>= 1) { sum += __shfl_xor(sum, off); sq += __shfl_xor(sq, off); }
  __shared__ float red[8];
  const int wid = tid >> 6;
  if ((tid & 63) == 0) { red[wid] = sum; red[4 + wid] = sq; }
  __syncthreads();
  sum = red[0] + red[1] + red[2] + red[3];
  sq = red[4] + red[5] + red[6] + red[7];
  const float mean = sum * (1.f / 1024.f);
  const float var = sq * (1.f / 1024.f) - mean * mean;
  const float rstd = rsqrtf(var + 1e-5f);
#pragma unroll
  for (int i = 0; i < 4; ++i) {
    const int d = tid + i * 256;
    const float y = (x[i] - mean) * rstd * g[d] + bb[d];
    s[d] = y;
    outb[(size_t)row * D_ + d] = f2bf(y);
  }
}

// ---------------------------------------------------------------------------
// Host orchestration
// ---------------------------------------------------------------------------
static inline int cdiv(int a, int b) { return (a + b - 1) / b; }

extern "C" void kernel_launch(void* const* d_in, const int* in_sizes, int n_in,
                              void* d_out, int out_size, void* d_ws, size_t ws_size,
                              hipStream_t stream) {
  const float* x    = (const float*)d_in[0];
  const float* Wq   = (const float*)d_in[1];
  const float* Wk   = (const float*)d_in[2];
  const float* Wv   = (const float*)d_in[3];
  const float* Wpk  = (const float*)d_in[4];
  const float* bpk  = (const float*)d_in[5];
  const float* Wpv  = (const float*)d_in[6];
  const float* bpv  = (const float*)d_in[7];
  const float* g1   = (const float*)d_in[8];
  const float* b1ln = (const float*)d_in[9];
  const float* W1   = (const float*)d_in[10];
  const float* b1   = (const float*)d_in[11];
  const float* W2   = (const float*)d_in[12];
  const float* b2   = (const float*)d_in[13];
  const float* g2   = (const float*)d_in[14];
  const float* b2ln = (const float*)d_in[15];

  char* wsb = (char*)d_ws;
  // Workspace map (~158.7 MB total):
  float* cosT = (float*)(wsb + 0);
  float* sinT = (float*)(wsb + 262144);
  float* srcf = (float*)(wsb + 524288);          // fp32 residual master (32.768 MB)
  u16* srcb   = (u16*)(wsb + 33292288);          // bf16 mirror
  u16* Qb     = (u16*)(wsb + 49676288);
  u16* Kb     = (u16*)(wsb + 66060288);
  u16* Vb     = (u16*)(wsb + 82444288);
  u16* Km     = (u16*)(wsb + 98828288);
  u16* Vm     = (u16*)(wsb + 115212288);
  u16* wbuf   = (u16*)(wsb + 131596288);         // per-layer bf16 weights (27.07 MB)
  u16* hB     = Qb;  // (B,T,DFF) bf16 overlaps Qb..Km (dead after attention)

  u16* wqB  = wbuf + 0;
  u16* wkB  = wbuf + 1048576;
  u16* wvB  = wbuf + 2097152;
  u16* wpkB = wbuf + 3145728;
  u16* wpvB = wbuf + 4145728;
  u16* w1B  = wbuf + 5145728;
  u16* w2B  = wbuf + 9340032;

  float* yF = (float*)d_out;  // fp32 scratch for attention-out / FFN2-out

  tab_kernel<<<250, 256, 0, stream>>>(cosT, sinT);
  hipMemcpyAsync(srcf, x, (size_t)BT_ * D_ * sizeof(float), hipMemcpyDeviceToDevice, stream);
  convert_kernel<<<cdiv(BT_ * D_, 1024), 256, 0, stream>>>(x, srcb, BT_ * D_);

  for (int l = 0; l < 4; ++l) {
    convert_kernel<<<cdiv(1048576, 1024), 256, 0, stream>>>(Wq + (size_t)l * 1048576, wqB, 1048576);
    convert_kernel<<<cdiv(1048576, 1024), 256, 0, stream>>>(Wk + (size_t)l * 1048576, wkB, 1048576);
    convert_kernel<<<cdiv(1048576, 1024), 256, 0, stream>>>(Wv + (size_t)l * 1048576, wvB, 1048576);
    convert_kernel<<<cdiv(1000000, 1024), 256, 0, stream>>>(Wpk + (size_t)l * 1000000, wpkB, 1000000);
    convert_kernel<<<cdiv(1000000, 1024), 256, 0, stream>>>(Wpv + (size_t)l * 1000000, wpvB, 1000000);
    convert_kernel<<<cdiv(4194304, 1024), 256, 0, stream>>>(W1 + (size_t)l * 4194304, w1B, 4194304);
    convert_kernel<<<cdiv(4194304, 1024), 256, 0, stream>>>(W2 + (size_t)l * 4194304, w2B, 4194304);

    // Q/K/V projections: (8000x1024) = src (8000x1024) x W^T  [NT]
    gemm_kernel<0, false, false, true><<<dim3(8, 63, 1), 256, 0, stream>>>(
        srcb, wqB, Qb, nullptr, BT_, 1024, 1024, 1024, 1024, 1024, 0, 0, 0);
    gemm_kernel<0, false, false, true><<<dim3(8, 63, 1), 256, 0, stream>>>(
        srcb, wkB, Kb, nullptr, BT_, 1024, 1024, 1024, 1024, 1024, 0, 0, 0);
    gemm_kernel<0, false, false, true><<<dim3(8, 63, 1), 256, 0, stream>>>(
        srcb, wvB, Vb, nullptr, BT_, 1024, 1024, 1024, 1024, 1024, 0, 0, 0);

    // Position mix: Km[b,u,d] = sum_t Wpk[u,t]*K[b,t,d] + bpk[u]   [B k-major, batched]
    gemm_kernel<1, true, false, true><<<dim3(8, 8, 8), 256, 0, stream>>>(
        wpkB, Kb, Km, bpk + (size_t)l * 1000, 1000, 1024, 1000, 1000, 1024, 1024,
        0L, 1024000L, 1024000L);
    gemm_kernel<1, true, false, true><<<dim3(8, 8, 8), 256, 0, stream>>>(
        wpvB, Vb, Vm, bpv + (size_t)l * 1000, 1000, 1024, 1000, 1000, 1024, 1024,
        0L, 1024000L, 1024000L);

    rope_kernel<<<16000, 256, 0, stream>>>(Qb, cosT, sinT);
    rope_kernel<<<16000, 256, 0, stream>>>(Km, cosT, sinT);

    attn_kernel<<<dim3(16, 64), 256, 0, stream>>>(Qb, Km, Vm, yF);

    addln_kernel<<<BT_, 256, 0, stream>>>(srcf, yF, g1 + (size_t)l * 1024,
                                          b1ln + (size_t)l * 1024, srcb);

    // FFN1 with fused exact gelu -> bf16 h
    gemm_kernel<2, false, true, true><<<dim3(32, 63, 1), 256, 0, stream>>>(
        srcb, w1B, hB, b1 + (size_t)l * 4096, BT_, 4096, 1024, 1024, 1024, 4096, 0, 0, 0);
    // FFN2 -> fp32 into d_out
    gemm_kernel<2, false, false, false><<<dim3(8, 63, 1), 256, 0, stream>>>(
        hB, w2B, d_out, b2 + (size_t)l * 1024, BT_, 1024, 4096, 4096, 4096, 1024, 0, 0, 0);

    addln_kernel<<<BT_, 256, 0, stream>>>(srcf, yF, g2 + (size_t)l * 1024,
                                          b2ln + (size_t)l * 1024, srcb);
  }

  hipMemcpyAsync(d_out, srcf, (size_t)BT_ * D_ * sizeof(float), hipMemcpyDeviceToDevice, stream);
}

// Round 2
// 2519.663 us; speedup vs baseline: 1.2594x; 1.2594x over previous
//
#include <hip/hip_runtime.h>
#include <cstdint>
#include <cstddef>

// ---------------------------------------------------------------------------
// SelfAttentionTransformer on MI355X (gfx950).
// L=4, D=1024, H=8, HS=128, T=1000, DFF=4096, B=8.
// bf16 MFMA (16x16x32) everywhere GEMM-shaped; fp32 residual/LN master.
// R1: m97-structure NT GEMM (global_load_lds width-16, linear LDS, BK=32),
//     fused QKV projection (N=3072).
// ---------------------------------------------------------------------------

typedef unsigned short u16;
typedef unsigned int u32;
typedef __attribute__((ext_vector_type(8))) short s16x8;   // 8 bf16 raw bits
typedef __attribute__((ext_vector_type(4))) float f32x4;

#define DEV static __device__ __forceinline__

DEV float bf2f(u16 u) { union { u32 u; float f; } v; v.u = ((u32)u) << 16; return v.f; }
DEV u16 f2bf(float f) {
  union { float f; u32 u; } v; v.f = f;
  return (u16)((v.u + 0x7fffu + ((v.u >> 16) & 1u)) >> 16);   // RNE
}

#define MFMA(acc_, a_, b_) \
  asm volatile("v_mfma_f32_16x16x32_bf16 %0, %1, %2, %0" : "+v"(acc_) : "v"(a_), "v"(b_))

// async global->LDS, 16B per lane. Dest is wave-uniform base + lane*16.
#define GLD16(g_, l_) \
  __builtin_amdgcn_global_load_lds((const __attribute__((address_space(1))) void*)(g_), \
                                   (__attribute__((address_space(3))) void*)(l_), 16, 0, 0)

static constexpr int T_ = 1000, D_ = 1024, H_ = 8, HS_ = 128, B_ = 8;
static constexpr int BT_ = B_ * T_;   // 8000

// ---------------------------------------------------------------------------
// RoPE cos/sin table
// ---------------------------------------------------------------------------
__global__ void tab_kernel(float* __restrict__ ct, float* __restrict__ st) {
  const int id = blockIdx.x * 256 + threadIdx.x;   // 64000
  const int i = id & 63, t = id >> 6;
  const float theta = powf(10000.f, -(float)i * (1.f / 64.f));
  const float ang = (float)t * theta;
  ct[id] = cosf(ang);
  st[id] = sinf(ang);
}

__global__ void convert_kernel(const float* __restrict__ in, u16* __restrict__ out, int n) {
  const int i = (blockIdx.x * 256 + threadIdx.x) * 4;
  if (i < n) {
    const float4 v = *(const float4*)(in + i);
    uint2 pk;
    pk.x = (u32)f2bf(v.x) | ((u32)f2bf(v.y) << 16);
    pk.y = (u32)f2bf(v.z) | ((u32)f2bf(v.w) << 16);
    *(uint2*)(out + i) = pk;
  }
}

// ---------------------------------------------------------------------------
// Fast NT GEMM (m97 structure): C[m,n] = sum_k A[m,k]*B[n,k] (+bias/gelu).
// Requires: K % 32 == 0, N % 128 == 0. M tail via row-clamp.
// 128x128 tile, BK=32, linear LDS, global_load_lds dwordx4 staging.
// ---------------------------------------------------------------------------
template <int BIAS, bool ACT, bool OUTBF>   // BIAS: 0 none, 1 row, 2 col
__global__ __launch_bounds__(256) void gemm_nt(
    const u16* __restrict__ A, const u16* __restrict__ B, void* __restrict__ Cv,
    const float* __restrict__ bias, int M, int N, int K, int lda, int ldb, int ldc,
    long sB, long sC) {
  __shared__ alignas(16) u16 As[128 * 32];
  __shared__ alignas(16) u16 Bs[128 * 32];
  const int z = blockIdx.z;
  B += (size_t)z * (size_t)sB;
  const int m0 = blockIdx.y * 128, n0 = blockIdx.x * 128;
  const int tid = threadIdx.x;
  const int wid = tid >> 6, lane = tid & 63;
  const int wr = wid >> 1, wc = wid & 1;
  const int l15 = lane & 15, l4 = lane >> 4;
  // staging: chunk = tid (+256), row = chunk>>2, col = (chunk&3)*8
  const int srow = tid >> 2, scol = (tid & 3) << 3;
  const int mA0 = min(m0 + srow, M - 1);
  const int mA1 = min(m0 + 64 + srow, M - 1);
  const u16* gA0 = A + (size_t)mA0 * lda + scol;
  const u16* gA1 = A + (size_t)mA1 * lda + scol;
  const u16* gB0 = B + (size_t)(n0 + srow) * ldb + scol;
  const u16* gB1 = B + (size_t)(n0 + 64 + srow) * ldb + scol;
  u16* lA0 = As + tid * 8;  u16* lA1 = As + (256 + tid) * 8;
  u16* lB0 = Bs + tid * 8;  u16* lB1 = Bs + (256 + tid) * 8;
  f32x4 acc[4][4] = {};
  const int KT = K >> 5;
  for (int kt = 0; kt < KT; ++kt) {
    const int kb = kt << 5;
    GLD16(gA0 + kb, lA0);
    GLD16(gA1 + kb, lA1);
    GLD16(gB0 + kb, lB0);
    GLD16(gB1 + kb, lB1);
    __syncthreads();   // vmcnt(0) drain: tile resident
    s16x8 af[4], bfr[4];
#pragma unroll
    for (int i = 0; i < 4; ++i)
      af[i] = *(const s16x8*)&As[(wr * 64 + i * 16 + l15) * 32 + l4 * 8];
#pragma unroll
    for (int i = 0; i < 4; ++i)
      bfr[i] = *(const s16x8*)&Bs[(wc * 64 + i * 16 + l15) * 32 + l4 * 8];
#pragma unroll
    for (int mi = 0; mi < 4; ++mi)
#pragma unroll
      for (int ni = 0; ni < 4; ++ni) MFMA(acc[mi][ni], af[mi], bfr[ni]);
    __syncthreads();   // reads done before next-tile staging
  }
  asm volatile("s_nop 7\n\ts_nop 7"
               : "+v"(acc[3][0]), "+v"(acc[3][1]), "+v"(acc[3][2]), "+v"(acc[3][3]));
#pragma unroll
  for (int mi = 0; mi < 4; ++mi) {
#pragma unroll
    for (int ni = 0; ni < 4; ++ni) {
      const int colg = n0 + wc * 64 + ni * 16 + l15;
#pragma unroll
      for (int r = 0; r < 4; ++r) {
        const int rowg = m0 + wr * 64 + mi * 16 + l4 * 4 + r;
        if (rowg < M) {
          float v = acc[mi][ni][r];
          if (BIAS == 1) v += bias[rowg];
          if (BIAS == 2) v += bias[colg];
          if (ACT) v = 0.5f * v * (1.0f + erff(v * 0.70710678118654752f));
          const size_t idx = (size_t)z * (size_t)sC + (size_t)rowg * ldc + colg;
          if (OUTBF) ((u16*)Cv)[idx] = f2bf(v);
          else       ((float*)Cv)[idx] = v;
        }
      }
    }
  }
}

// ---------------------------------------------------------------------------
// Guarded k-major GEMM (for the position mix, K=1000 tail + B k-major).
// C[m,n] = sum_k A[m,k]*B[k*ldb+n] + bias[m].  (proven round-0 path)
// ---------------------------------------------------------------------------
__global__ __launch_bounds__(256) void gemm_bkm(
    const u16* __restrict__ A, const u16* __restrict__ B, u16* __restrict__ C,
    const float* __restrict__ bias, int M, int N, int K, int lda, int ldb, int ldc,
    long sB, long sC) {
  __shared__ alignas(16) u16 As[128][40];
  __shared__ alignas(16) u16 Bs[128][40];
  const int z = blockIdx.z;
  B += (size_t)z * (size_t)sB;
  const int m0 = blockIdx.y * 128, n0 = blockIdx.x * 128;
  const int tid = threadIdx.x;
  const int wid = tid >> 6, lane = tid & 63;
  const int wr = wid >> 1, wc = wid & 1;
  const int l15 = lane & 15, l4 = lane >> 4;
  f32x4 acc[4][4] = {};
  const int KT = (K + 31) >> 5;
  for (int kt = 0; kt < KT; ++kt) {
    const int kbase = kt << 5;
    {  // A tile
      const int row = tid >> 1, koff = (tid & 1) << 4;
      const int gm = m0 + row;
#pragma unroll
      for (int v = 0; v < 2; ++v) {
        const int k0 = kbase + koff + v * 8;
        s16x8 val = {};
        if (gm < M) {
          if (k0 + 8 <= K) val = *(const s16x8*)(A + (size_t)gm * lda + k0);
          else {
#pragma unroll
            for (int j = 0; j < 8; ++j) { const int kk = k0 + j; if (kk < K) val[j] = (short)A[(size_t)gm * lda + kk]; }
          }
        }
        *(s16x8*)&As[row][koff + v * 8] = val;
      }
    }
    {  // B tile, k-major: read rows of n, transpose into Bs[n][k]
      const int kk = tid >> 3, nof = (tid & 7) << 4;
      const int gk = kbase + kk;
#pragma unroll
      for (int v = 0; v < 2; ++v) {
        const int nb = nof + v * 8;
        const int gn = n0 + nb;
        s16x8 val = {};
        if (gk < K) {
          if (gn + 8 <= N) val = *(const s16x8*)(B + (size_t)gk * ldb + gn);
          else {
#pragma unroll
            for (int j = 0; j < 8; ++j) { if (gn + j < N) val[j] = (short)B[(size_t)gk * ldb + gn + j]; }
          }
        }
#pragma unroll
        for (int j = 0; j < 8; ++j) Bs[nb + j][kk] = (u16)val[j];
      }
    }
    __syncthreads();
    s16x8 af[4], bfr[4];
#pragma unroll
    for (int i = 0; i < 4; ++i) af[i] = *(const s16x8*)&As[wr * 64 + i * 16 + l15][l4 * 8];
#pragma unroll
    for (int i = 0; i < 4; ++i) bfr[i] = *(const s16x8*)&Bs[wc * 64 + i * 16 + l15][l4 * 8];
#pragma unroll
    for (int mi = 0; mi < 4; ++mi)
#pragma unroll
      for (int ni = 0; ni < 4; ++ni) MFMA(acc[mi][ni], af[mi], bfr[ni]);
    __syncthreads();
  }
  asm volatile("s_nop 7\n\ts_nop 7"
               : "+v"(acc[3][0]), "+v"(acc[3][1]), "+v"(acc[3][2]), "+v"(acc[3][3]));
#pragma unroll
  for (int mi = 0; mi < 4; ++mi) {
#pragma unroll
    for (int ni = 0; ni < 4; ++ni) {
      const int colg = n0 + wc * 64 + ni * 16 + l15;
#pragma unroll
      for (int r = 0; r < 4; ++r) {
        const int rowg = m0 + wr * 64 + mi * 16 + l4 * 4 + r;
        if (rowg < M && colg < N) {
          float v = acc[mi][ni][r] + bias[rowg];
          C[(size_t)z * (size_t)sC + (size_t)rowg * ldc + colg] = f2bf(v);
        }
      }
    }
  }
}

// ---------------------------------------------------------------------------
// RoPE in place on a bf16 buffer with row stride ld.
// ---------------------------------------------------------------------------
__global__ __launch_bounds__(256) void rope_kernel(u16* __restrict__ X, int ld,
                                                   const float* __restrict__ ct,
                                                   const float* __restrict__ st) {
  const int id = blockIdx.x * 256 + threadIdx.x;  // 4,096,000
  const int i = id & 63;
  const int h = (id >> 6) & 7;
  const int bt = id >> 9;
  const int t = bt % 1000;
  const size_t base = (size_t)bt * ld + h * HS_ + i * 2;
  u32* p = (u32*)(X + base);
  const u32 w = *p;
  const float xr = bf2f((u16)(w & 0xffffu));
  const float xi = bf2f((u16)(w >> 16));
  const float c = ct[t * 64 + i], s = st[t * 64 + i];
  const float outr = xr * c - xi * s;
  const float outi = xr * s + xi * c;
  *p = (u32)f2bf(outr) | ((u32)f2bf(outi) << 16);
}

// ---------------------------------------------------------------------------
// Flash attention (non-causal). Q has row stride ldq; K/V stride 1024.
// ---------------------------------------------------------------------------
__global__ __launch_bounds__(256) void attn_kernel(const u16* __restrict__ Q, int ldq,
                                                   const u16* __restrict__ Kr,
                                                   const u16* __restrict__ V,
                                                   float* __restrict__ Y) {
  __shared__ alignas(16) u16 Ks[64][136];
  __shared__ alignas(16) u16 Vt[128][72];
  __shared__ alignas(16) u16 Ps[4][16][72];
  const int qt = blockIdx.x;
  const int bh = blockIdx.y;
  const int b = bh >> 3, h = bh & 7;
  const int tid = threadIdx.x;
  const int w = tid >> 6, lane = tid & 63;
  const int l15 = lane & 15, l4 = lane >> 4;
  const size_t headQ = (size_t)b * T_ * ldq + h * HS_;
  const size_t headK = (size_t)b * T_ * D_ + h * HS_;
  const int qrow = qt * 64 + w * 16 + l15;
  s16x8 aq[4];
#pragma unroll
  for (int c = 0; c < 4; ++c) {
    s16x8 v = {};
    if (qrow < T_) v = *(const s16x8*)(Q + headQ + (size_t)qrow * ldq + c * 32 + l4 * 8);
    aq[c] = v;
  }
  f32x4 acc[8] = {};
  float m_run[4], l_run[4];
#pragma unroll
  for (int r = 0; r < 4; ++r) { m_run[r] = -1e30f; l_run[r] = 0.f; }
  const float SCALE = 0.08838834764831845f;
  for (int kt = 0; kt < 16; ++kt) {
    {
      const int r = tid >> 2, c0 = (tid & 3) << 5;
      const int kk = kt * 64 + r;
#pragma unroll
      for (int v = 0; v < 4; ++v) {
        s16x8 val = {};
        if (kk < T_) val = *(const s16x8*)(Kr + headK + (size_t)kk * D_ + c0 + v * 8);
        *(s16x8*)&Ks[r][c0 + v * 8] = val;
      }
#pragma unroll
      for (int v = 0; v < 4; ++v) {
        s16x8 val = {};
        if (kk < T_) val = *(const s16x8*)(V + headK + (size_t)kk * D_ + c0 + v * 8);
#pragma unroll
        for (int j = 0; j < 8; ++j) Vt[c0 + v * 8 + j][r] = (u16)val[j];
      }
    }
    __syncthreads();
    f32x4 sacc[4] = {};
#pragma unroll
    for (int c = 0; c < 4; ++c)
#pragma unroll
      for (int f = 0; f < 4; ++f) {
        s16x8 bk = *(const s16x8*)&Ks[f * 16 + l15][c * 32 + l4 * 8];
        MFMA(sacc[f], aq[c], bk);
      }
    asm volatile("s_nop 7\n\ts_nop 7"
                 : "+v"(sacc[0]), "+v"(sacc[1]), "+v"(sacc[2]), "+v"(sacc[3]));
    float sv[4][4];
#pragma unroll
    for (int f = 0; f < 4; ++f) {
      const int key = kt * 64 + f * 16 + l15;
#pragma unroll
      for (int r = 0; r < 4; ++r) sv[f][r] = (key < T_) ? sacc[f][r] * SCALE : -1e30f;
    }
#pragma unroll
    for (int r = 0; r < 4; ++r) {
      float mx = fmaxf(fmaxf(sv[0][r], sv[1][r]), fmaxf(sv[2][r], sv[3][r]));
#pragma unroll
      for (int off = 8; off >= 1; off >>= 1) mx = fmaxf(mx, __shfl_xor(mx, off));
      const float mn = fmaxf(m_run[r], mx);
      const float corr = __expf(m_run[r] - mn);
      m_run[r] = mn;
      float rs = 0.f;
#pragma unroll
      for (int f = 0; f < 4; ++f) {
        const float p = __expf(sv[f][r] - mn);
        rs += p;
        Ps[w][l4 * 4 + r][f * 16 + l15] = f2bf(p);
      }
#pragma unroll
      for (int off = 8; off >= 1; off >>= 1) rs += __shfl_xor(rs, off);
      l_run[r] = l_run[r] * corr + rs;
#pragma unroll
      for (int n = 0; n < 8; ++n) acc[n][r] *= corr;
    }
    __syncthreads();
#pragma unroll
    for (int c2 = 0; c2 < 2; ++c2) {
      const s16x8 pa = *(const s16x8*)&Ps[w][l15][c2 * 32 + l4 * 8];
#pragma unroll
      for (int n = 0; n < 8; ++n) {
        const s16x8 vb = *(const s16x8*)&Vt[n * 16 + l15][c2 * 32 + l4 * 8];
        MFMA(acc[n], pa, vb);
      }
    }
    __syncthreads();
  }
  asm volatile("s_nop 7\n\ts_nop 7"
               : "+v"(acc[4]), "+v"(acc[5]), "+v"(acc[6]), "+v"(acc[7]));
#pragma unroll
  for (int n = 0; n < 8; ++n)
#pragma unroll
    for (int r = 0; r < 4; ++r) {
      const int q = qt * 64 + w * 16 + l4 * 4 + r;
      if (q < T_) Y[headK + (size_t)q * D_ + n * 16 + l15] = acc[n][r] / l_run[r];
    }
}

// ---------------------------------------------------------------------------
// src = LN(src + add) * g + b  (fp32 master) + bf16 mirror.
// ---------------------------------------------------------------------------
__global__ __launch_bounds__(256) void addln_kernel(float* __restrict__ src,
                                                    const float* __restrict__ add,
                                                    const float* __restrict__ g,
                                                    const float* __restrict__ bb,
                                                    u16* __restrict__ outb) {
  const int row = blockIdx.x;
  const int tid = threadIdx.x;
  float* s = src + (size_t)row * D_;
  const float* a = add + (size_t)row * D_;
  float x[4];
  float sum = 0.f, sq = 0.f;
#pragma unroll
  for (int i = 0; i < 4; ++i) {
    const int d = tid + i * 256;
    const float v = s[d] + a[d];
    x[i] = v; sum += v; sq += v * v;
  }
#pragma unroll
  for (int off = 32; off >= 1; off >>= 1) { sum += __shfl_xor(sum, off); sq += __shfl_xor(sq, off); }
  __shared__ float red[8];
  const int wid = tid >> 6;
  if ((tid & 63) == 0) { red[wid] = sum; red[4 + wid] = sq; }
  __syncthreads();
  sum = red[0] + red[1] + red[2] + red[3];
  sq = red[4] + red[5] + red[6] + red[7];
  const float mean = sum * (1.f / 1024.f);
  const float var = sq * (1.f / 1024.f) - mean * mean;
  const float rstd = rsqrtf(var + 1e-5f);
#pragma unroll
  for (int i = 0; i < 4; ++i) {
    const int d = tid + i * 256;
    const float y = (x[i] - mean) * rstd * g[d] + bb[d];
    s[d] = y;
    outb[(size_t)row * D_ + d] = f2bf(y);
  }
}

// ---------------------------------------------------------------------------
// Host orchestration
// ---------------------------------------------------------------------------
static inline int cdiv(int a, int b) { return (a + b - 1) / b; }

extern "C" void kernel_launch(void* const* d_in, const int* in_sizes, int n_in,
                              void* d_out, int out_size, void* d_ws, size_t ws_size,
                              hipStream_t stream) {
  const float* x    = (const float*)d_in[0];
  const float* Wq   = (const float*)d_in[1];
  const float* Wk   = (const float*)d_in[2];
  const float* Wv   = (const float*)d_in[3];
  const float* Wpk  = (const float*)d_in[4];
  const float* bpk  = (const float*)d_in[5];
  const float* Wpv  = (const float*)d_in[6];
  const float* bpv  = (const float*)d_in[7];
  const float* g1   = (const float*)d_in[8];
  const float* b1ln = (const float*)d_in[9];
  const float* W1   = (const float*)d_in[10];
  const float* b1   = (const float*)d_in[11];
  const float* W2   = (const float*)d_in[12];
  const float* b2   = (const float*)d_in[13];
  const float* g2   = (const float*)d_in[14];
  const float* b2ln = (const float*)d_in[15];

  char* wsb = (char*)d_ws;
  // Workspace map — byte-identical extents to the proven round-0 layout:
  float* cosT = (float*)(wsb + 0);
  float* sinT = (float*)(wsb + 262144);
  float* srcf = (float*)(wsb + 524288);          // fp32 residual (32.768 MB)
  u16* srcb   = (u16*)(wsb + 33292288);          // bf16 mirror
  u16* QKVb   = (u16*)(wsb + 49676288);          // [8000][3072] fused QKV (49.152 MB)
  u16* Km     = (u16*)(wsb + 98828288);          // [8][1000][1024]
  u16* Vm     = (u16*)(wsb + 115212288);
  u16* wbuf   = (u16*)(wsb + 131596288);         // per-layer bf16 weights
  u16* hB     = QKVb;  // (8000,4096) bf16 == QKVb+Km extents exactly; dead overlap

  u16* wqB  = wbuf + 0;          // [3072][1024] contiguous q,k,v
  u16* wpkB = wbuf + 3145728;    // [1000][1000]
  u16* wpvB = wbuf + 4145728;
  u16* w1B  = wbuf + 5145728;    // [4096][1024]
  u16* w2B  = wbuf + 9340032;    // [1024][4096]

  float* yF = (float*)d_out;  // attention-out scratch (fp32), later FFN2 out

  tab_kernel<<<250, 256, 0, stream>>>(cosT, sinT);
  hipMemcpyAsync(srcf, x, (size_t)BT_ * D_ * sizeof(float), hipMemcpyDeviceToDevice, stream);
  convert_kernel<<<cdiv(BT_ * D_, 1024), 256, 0, stream>>>(x, srcb, BT_ * D_);

  for (int l = 0; l < 4; ++l) {
    convert_kernel<<<cdiv(1048576, 1024), 256, 0, stream>>>(Wq + (size_t)l * 1048576, wqB, 1048576);
    convert_kernel<<<cdiv(1048576, 1024), 256, 0, stream>>>(Wk + (size_t)l * 1048576, wqB + 1048576, 1048576);
    convert_kernel<<<cdiv(1048576, 1024), 256, 0, stream>>>(Wv + (size_t)l * 1048576, wqB + 2097152, 1048576);
    convert_kernel<<<cdiv(1000000, 1024), 256, 0, stream>>>(Wpk + (size_t)l * 1000000, wpkB, 1000000);
    convert_kernel<<<cdiv(1000000, 1024), 256, 0, stream>>>(Wpv + (size_t)l * 1000000, wpvB, 1000000);
    convert_kernel<<<cdiv(4194304, 1024), 256, 0, stream>>>(W1 + (size_t)l * 4194304, w1B, 4194304);
    convert_kernel<<<cdiv(4194304, 1024), 256, 0, stream>>>(W2 + (size_t)l * 4194304, w2B, 4194304);

    // Fused QKV: (8000x3072) = srcb (8000x1024) x [Wq;Wk;Wv]^T
    gemm_nt<0, false, true><<<dim3(24, 63, 1), 256, 0, stream>>>(
        srcb, wqB, QKVb, nullptr, BT_, 3072, 1024, 1024, 1024, 3072, 0, 0);

    // Position mix (k-major B): Km[b,u,d] = sum_t Wpk[u,t]*K[b,t,d] + bpk[u]
    gemm_bkm<<<dim3(8, 8, 8), 256, 0, stream>>>(
        wpkB, QKVb + 1024, Km, bpk + (size_t)l * 1000, 1000, 1024, 1000,
        1000, 3072, 1024, 3072000L, 1024000L);
    gemm_bkm<<<dim3(8, 8, 8), 256, 0, stream>>>(
        wpvB, QKVb + 2048, Vm, bpv + (size_t)l * 1000, 1000, 1024, 1000,
        1000, 3072, 1024, 3072000L, 1024000L);

    rope_kernel<<<16000, 256, 0, stream>>>(QKVb, 3072, cosT, sinT);  // Q
    rope_kernel<<<16000, 256, 0, stream>>>(Km, 1024, cosT, sinT);

    attn_kernel<<<dim3(16, 64), 256, 0, stream>>>(QKVb, 3072, Km, Vm, yF);

    addln_kernel<<<BT_, 256, 0, stream>>>(srcf, yF, g1 + (size_t)l * 1024,
                                          b1ln + (size_t)l * 1024, srcb);

    // FFN1 (+bias+gelu) -> bf16 h
    gemm_nt<2, true, true><<<dim3(32, 63, 1), 256, 0, stream>>>(
        srcb, w1B, hB, b1 + (size_t)l * 4096, BT_, 4096, 1024, 1024, 1024, 4096, 0, 0);
    // FFN2 (+bias) -> fp32 d_out
    gemm_nt<2, false, false><<<dim3(8, 63, 1), 256, 0, stream>>>(
        hB, w2B, d_out, b2 + (size_t)l * 1024, BT_, 1024, 4096, 4096, 4096, 1024, 0, 0);

    addln_kernel<<<BT_, 256, 0, stream>>>(srcf, yF, g2 + (size_t)l * 1024,
                                          b2ln + (size_t)l * 1024, srcb);
  }

  hipMemcpyAsync(d_out, srcf, (size_t)BT_ * D_ * sizeof(float), hipMemcpyDeviceToDevice, stream);
}

// Round 3
// 2284.049 us; speedup vs baseline: 1.3893x; 1.1032x over previous
//
#include <hip/hip_runtime.h>
#include <cstdint>
#include <cstddef>

// ---------------------------------------------------------------------------
// SelfAttentionTransformer on MI355X (gfx950).
// L=4, D=1024, H=8, HS=128, T=1000, DFF=4096, B=8.
// bf16 MFMA (16x16x32) everywhere; fp32 residual/LN master.
// R2: QBLK=128 flash attention; V^T produced by swapped NT mix GEMM;
//     K/V pre-transpose kernel so both position-mixes ride the fast
//     global_load_lds NT GEMM path.
// ---------------------------------------------------------------------------

typedef unsigned short u16;
typedef unsigned int u32;
typedef __attribute__((ext_vector_type(8))) short s16x8;   // 8 bf16 raw bits
typedef __attribute__((ext_vector_type(4))) float f32x4;

#define DEV static __device__ __forceinline__

DEV float bf2f(u16 u) { union { u32 u; float f; } v; v.u = ((u32)u) << 16; return v.f; }
DEV u16 f2bf(float f) {
  union { float f; u32 u; } v; v.f = f;
  return (u16)((v.u + 0x7fffu + ((v.u >> 16) & 1u)) >> 16);   // RNE
}

#define MFMA(acc_, a_, b_) \
  asm volatile("v_mfma_f32_16x16x32_bf16 %0, %1, %2, %0" : "+v"(acc_) : "v"(a_), "v"(b_))

// async global->LDS, 16B per lane. Dest is wave-uniform base + lane*16.
#define GLD16(g_, l_) \
  __builtin_amdgcn_global_load_lds((const __attribute__((address_space(1))) void*)(g_), \
                                   (__attribute__((address_space(3))) void*)(l_), 16, 0, 0)

static constexpr int T_ = 1000, D_ = 1024, H_ = 8, HS_ = 128, B_ = 8;
static constexpr int BT_ = B_ * T_;   // 8000

// ---------------------------------------------------------------------------
__global__ void tab_kernel(float* __restrict__ ct, float* __restrict__ st) {
  const int id = blockIdx.x * 256 + threadIdx.x;   // 64000
  const int i = id & 63, t = id >> 6;
  const float theta = powf(10000.f, -(float)i * (1.f / 64.f));
  const float ang = (float)t * theta;
  ct[id] = cosf(ang);
  st[id] = sinf(ang);
}

__global__ void convert_kernel(const float* __restrict__ in, u16* __restrict__ out, int n) {
  const int i = (blockIdx.x * 256 + threadIdx.x) * 4;
  if (i < n) {
    const float4 v = *(const float4*)(in + i);
    uint2 pk;
    pk.x = (u32)f2bf(v.x) | ((u32)f2bf(v.y) << 16);
    pk.y = (u32)f2bf(v.z) | ((u32)f2bf(v.w) << 16);
    *(uint2*)(out + i) = pk;
  }
}

// ---------------------------------------------------------------------------
// Transpose a (t,d) slice of QKVb into out[b][d][t], t zero-padded to 1024.
// in: QKVb rows bt (stride 3072), cols cb..cb+1024. grid (16 tt, 16 dt, 8 b).
// ---------------------------------------------------------------------------
__global__ __launch_bounds__(256) void transpose_kernel(const u16* __restrict__ in,
                                                        u16* __restrict__ out, int cb) {
  __shared__ u16 tile[64][72];
  const int tt = blockIdx.x, dt = blockIdx.y, b = blockIdx.z;
  const int tid = threadIdx.x;
  const int r = tid >> 2, cq = (tid & 3) << 4;
  const int t = tt * 64 + r;
#pragma unroll
  for (int v = 0; v < 2; ++v) {
    s16x8 val = {};
    if (t < T_) val = *(const s16x8*)(in + (size_t)(b * 1000 + t) * 3072 + cb + dt * 64 + cq + v * 8);
    *(s16x8*)&tile[r][cq + v * 8] = val;
  }
  __syncthreads();
  const int d = dt * 64 + r;
  u16 vals[16];
#pragma unroll
  for (int j = 0; j < 16; ++j) vals[j] = tile[cq + j][r];
  u16* o = out + (size_t)b * 1048576 + (size_t)d * 1024 + tt * 64 + cq;
  *(s16x8*)o = *(s16x8*)&vals[0];
  *(s16x8*)(o + 8) = *(s16x8*)&vals[8];
}

// ---------------------------------------------------------------------------
// Fast NT GEMM (m97 structure): C[m,n] = sum_k A[m,k]*B[n,k] (+bias/gelu).
// Requires: K % 32 == 0 (zero-pad B-side if logical K smaller).
// M and N tails via row-clamp + store guard.
// ---------------------------------------------------------------------------
template <int BIAS, bool ACT, bool OUTBF>   // BIAS: 0 none, 1 row, 2 col
__global__ __launch_bounds__(256) void gemm_nt(
    const u16* __restrict__ A, const u16* __restrict__ B, void* __restrict__ Cv,
    const float* __restrict__ bias, int M, int N, int K, int lda, int ldb, int ldc,
    long sA, long sB, long sC) {
  __shared__ alignas(16) u16 As[128 * 32];
  __shared__ alignas(16) u16 Bs[128 * 32];
  const int z = blockIdx.z;
  A += (size_t)z * (size_t)sA;
  B += (size_t)z * (size_t)sB;
  const int m0 = blockIdx.y * 128, n0 = blockIdx.x * 128;
  const int tid = threadIdx.x;
  const int wid = tid >> 6, lane = tid & 63;
  const int wr = wid >> 1, wc = wid & 1;
  const int l15 = lane & 15, l4 = lane >> 4;
  const int srow = tid >> 2, scol = (tid & 3) << 3;
  const int mA0 = min(m0 + srow, M - 1);
  const int mA1 = min(m0 + 64 + srow, M - 1);
  const int nB0 = min(n0 + srow, N - 1);
  const int nB1 = min(n0 + 64 + srow, N - 1);
  const u16* gA0 = A + (size_t)mA0 * lda + scol;
  const u16* gA1 = A + (size_t)mA1 * lda + scol;
  const u16* gB0 = B + (size_t)nB0 * ldb + scol;
  const u16* gB1 = B + (size_t)nB1 * ldb + scol;
  u16* lA0 = As + tid * 8;  u16* lA1 = As + (256 + tid) * 8;
  u16* lB0 = Bs + tid * 8;  u16* lB1 = Bs + (256 + tid) * 8;
  f32x4 acc[4][4] = {};
  const int KT = K >> 5;
  for (int kt = 0; kt < KT; ++kt) {
    const int kb = kt << 5;
    GLD16(gA0 + kb, lA0);
    GLD16(gA1 + kb, lA1);
    GLD16(gB0 + kb, lB0);
    GLD16(gB1 + kb, lB1);
    __syncthreads();
    s16x8 af[4], bfr[4];
#pragma unroll
    for (int i = 0; i < 4; ++i)
      af[i] = *(const s16x8*)&As[(wr * 64 + i * 16 + l15) * 32 + l4 * 8];
#pragma unroll
    for (int i = 0; i < 4; ++i)
      bfr[i] = *(const s16x8*)&Bs[(wc * 64 + i * 16 + l15) * 32 + l4 * 8];
#pragma unroll
    for (int mi = 0; mi < 4; ++mi)
#pragma unroll
      for (int ni = 0; ni < 4; ++ni) MFMA(acc[mi][ni], af[mi], bfr[ni]);
    __syncthreads();
  }
  asm volatile("s_nop 7\n\ts_nop 7"
               : "+v"(acc[3][0]), "+v"(acc[3][1]), "+v"(acc[3][2]), "+v"(acc[3][3]));
#pragma unroll
  for (int mi = 0; mi < 4; ++mi) {
#pragma unroll
    for (int ni = 0; ni < 4; ++ni) {
      const int colg = n0 + wc * 64 + ni * 16 + l15;
#pragma unroll
      for (int r = 0; r < 4; ++r) {
        const int rowg = m0 + wr * 64 + mi * 16 + l4 * 4 + r;
        if (rowg < M && colg < N) {
          float v = acc[mi][ni][r];
          if (BIAS == 1) v += bias[rowg];
          if (BIAS == 2) v += bias[colg];
          if (ACT) v = 0.5f * v * (1.0f + erff(v * 0.70710678118654752f));
          const size_t idx = (size_t)z * (size_t)sC + (size_t)rowg * ldc + colg;
          if (OUTBF) ((u16*)Cv)[idx] = f2bf(v);
          else       ((float*)Cv)[idx] = v;
        }
      }
    }
  }
}

// ---------------------------------------------------------------------------
// RoPE in place, row stride ld (batch stride = 1000*ld).
// ---------------------------------------------------------------------------
__global__ __launch_bounds__(256) void rope_kernel(u16* __restrict__ X, int ld,
                                                   const float* __restrict__ ct,
                                                   const float* __restrict__ st) {
  const int id = blockIdx.x * 256 + threadIdx.x;  // 4,096,000
  const int i = id & 63;
  const int h = (id >> 6) & 7;
  const int bt = id >> 9;
  const int t = bt % 1000;
  const size_t base = (size_t)bt * ld + h * HS_ + i * 2;
  u32* p = (u32*)(X + base);
  const u32 w = *p;
  const float xr = bf2f((u16)(w & 0xffffu));
  const float xi = bf2f((u16)(w >> 16));
  const float c = ct[t * 64 + i], s = st[t * 64 + i];
  const float outr = xr * c - xi * s;
  const float outi = xr * s + xi * c;
  *p = (u32)f2bf(outr) | ((u32)f2bf(outi) << 16);
}

// ---------------------------------------------------------------------------
// Flash attention (non-causal), QBLK=128 (4 waves x 32 q-rows), KVBLK=64.
// Q: QKVb cols 0..1023 (stride ldq). Km: [b][1000][1024]. Vmt: [b][1024 d][1024 keys].
// ---------------------------------------------------------------------------
__global__ __launch_bounds__(256) void attn_kernel(const u16* __restrict__ Q, int ldq,
                                                   const u16* __restrict__ Km,
                                                   const u16* __restrict__ Vmt,
                                                   float* __restrict__ Y) {
  __shared__ alignas(16) u16 Ks[64][136];
  __shared__ alignas(16) u16 Vts[128][72];
  __shared__ alignas(16) u16 Ps[4][32][72];
  const int qt = blockIdx.x;                  // 8 q-tiles of 128
  const int bh = blockIdx.y;
  const int b = bh >> 3, h = bh & 7;
  const int tid = threadIdx.x;
  const int w = tid >> 6, lane = tid & 63;
  const int l15 = lane & 15, l4 = lane >> 4;
  const size_t qbase = (size_t)b * 1000 * ldq + h * HS_;
  const size_t kbase = (size_t)b * 1024000 + h * HS_;
  const size_t vbase = (size_t)b * 1048576 + (size_t)(h * HS_) * 1024;
  const int q0 = qt * 128 + w * 32;
  s16x8 aq[2][4];
#pragma unroll
  for (int qf = 0; qf < 2; ++qf) {
    const int qrow = q0 + qf * 16 + l15;
#pragma unroll
    for (int c = 0; c < 4; ++c) {
      s16x8 v = {};
      if (qrow < T_) v = *(const s16x8*)(Q + qbase + (size_t)qrow * ldq + c * 32 + l4 * 8);
      aq[qf][c] = v;
    }
  }
  f32x4 acc[2][8] = {};
  float m_run[2][4], l_run[2][4];
#pragma unroll
  for (int qf = 0; qf < 2; ++qf)
#pragma unroll
    for (int r = 0; r < 4; ++r) { m_run[qf][r] = -1e30f; l_run[qf][r] = 0.f; }
  const float SCALE = 0.08838834764831845f;
  for (int kt = 0; kt < 16; ++kt) {
    {  // stage K (row-major) and V^T (vector copy, no transpose needed)
      const int r = tid >> 2, c0 = (tid & 3) << 5;
      const int kk = kt * 64 + r;
#pragma unroll
      for (int v = 0; v < 4; ++v) {
        s16x8 val = {};
        if (kk < T_) val = *(const s16x8*)(Km + kbase + (size_t)kk * 1024 + c0 + v * 8);
        *(s16x8*)&Ks[r][c0 + v * 8] = val;
      }
      const int r2 = tid >> 1, c2s = (tid & 1) << 5;
#pragma unroll
      for (int v = 0; v < 4; ++v) {
        const s16x8 val = *(const s16x8*)(Vmt + vbase + (size_t)r2 * 1024 + kt * 64 + c2s + v * 8);
        *(s16x8*)&Vts[r2][c2s + v * 8] = val;
      }
    }
    __syncthreads();
    // S = Q K^T : per wave 32 q-rows x 64 keys
    f32x4 sacc[2][4] = {};
#pragma unroll
    for (int c = 0; c < 4; ++c) {
      s16x8 bk[4];
#pragma unroll
      for (int f = 0; f < 4; ++f) bk[f] = *(const s16x8*)&Ks[f * 16 + l15][c * 32 + l4 * 8];
#pragma unroll
      for (int qf = 0; qf < 2; ++qf)
#pragma unroll
        for (int f = 0; f < 4; ++f) MFMA(sacc[qf][f], aq[qf][c], bk[f]);
    }
    asm volatile("s_nop 7\n\ts_nop 7"
                 : "+v"(sacc[0][0]), "+v"(sacc[0][1]), "+v"(sacc[0][2]), "+v"(sacc[0][3]),
                   "+v"(sacc[1][0]), "+v"(sacc[1][1]), "+v"(sacc[1][2]), "+v"(sacc[1][3]));
#pragma unroll
    for (int qf = 0; qf < 2; ++qf) {
      float sv[4][4];
#pragma unroll
      for (int f = 0; f < 4; ++f) {
        const int key = kt * 64 + f * 16 + l15;
#pragma unroll
        for (int r = 0; r < 4; ++r) sv[f][r] = (key < T_) ? sacc[qf][f][r] * SCALE : -1e30f;
      }
#pragma unroll
      for (int r = 0; r < 4; ++r) {
        float mx = fmaxf(fmaxf(sv[0][r], sv[1][r]), fmaxf(sv[2][r], sv[3][r]));
#pragma unroll
        for (int off = 8; off >= 1; off >>= 1) mx = fmaxf(mx, __shfl_xor(mx, off));
        const float mn = fmaxf(m_run[qf][r], mx);
        const float corr = __expf(m_run[qf][r] - mn);
        m_run[qf][r] = mn;
        float rs = 0.f;
#pragma unroll
        for (int f = 0; f < 4; ++f) {
          const float p = __expf(sv[f][r] - mn);
          rs += p;
          Ps[w][qf * 16 + l4 * 4 + r][f * 16 + l15] = f2bf(p);
        }
#pragma unroll
        for (int off = 8; off >= 1; off >>= 1) rs += __shfl_xor(rs, off);
        l_run[qf][r] = l_run[qf][r] * corr + rs;
#pragma unroll
        for (int n = 0; n < 8; ++n) acc[qf][n][r] *= corr;
      }
    }
    asm volatile("s_waitcnt lgkmcnt(0)" ::: "memory");  // own-wave Ps writes -> reads
    // O += P V  (Vts rows d, cols keys)
#pragma unroll
    for (int c2 = 0; c2 < 2; ++c2) {
      s16x8 pa[2];
#pragma unroll
      for (int qf = 0; qf < 2; ++qf)
        pa[qf] = *(const s16x8*)&Ps[w][qf * 16 + l15][c2 * 32 + l4 * 8];
#pragma unroll
      for (int n = 0; n < 8; ++n) {
        const s16x8 vb = *(const s16x8*)&Vts[n * 16 + l15][c2 * 32 + l4 * 8];
#pragma unroll
        for (int qf = 0; qf < 2; ++qf) MFMA(acc[qf][n], pa[qf], vb);
      }
    }
    __syncthreads();  // protect Ks/Vts before next staging
  }
  asm volatile("s_nop 7\n\ts_nop 7"
               : "+v"(acc[0][6]), "+v"(acc[0][7]), "+v"(acc[1][6]), "+v"(acc[1][7]));
#pragma unroll
  for (int qf = 0; qf < 2; ++qf)
#pragma unroll
    for (int n = 0; n < 8; ++n)
#pragma unroll
      for (int r = 0; r < 4; ++r) {
        const int q = q0 + qf * 16 + l4 * 4 + r;
        if (q < T_)
          Y[(size_t)(b * 1000 + q) * 1024 + h * HS_ + n * 16 + l15] = acc[qf][n][r] / l_run[qf][r];
      }
}

// ---------------------------------------------------------------------------
// src = LN(src + add) * g + b  (fp32 master) + bf16 mirror.
// ---------------------------------------------------------------------------
__global__ __launch_bounds__(256) void addln_kernel(float* __restrict__ src,
                                                    const float* __restrict__ add,
                                                    const float* __restrict__ g,
                                                    const float* __restrict__ bb,
                                                    u16* __restrict__ outb) {
  const int row = blockIdx.x;
  const int tid = threadIdx.x;
  float* s = src + (size_t)row * D_;
  const float* a = add + (size_t)row * D_;
  float x[4];
  float sum = 0.f, sq = 0.f;
#pragma unroll
  for (int i = 0; i < 4; ++i) {
    const int d = tid + i * 256;
    const float v = s[d] + a[d];
    x[i] = v; sum += v; sq += v * v;
  }
#pragma unroll
  for (int off = 32; off >= 1; off >>= 1) { sum += __shfl_xor(sum, off); sq += __shfl_xor(sq, off); }
  __shared__ float red[8];
  const int wid = tid >> 6;
  if ((tid & 63) == 0) { red[wid] = sum; red[4 + wid] = sq; }
  __syncthreads();
  sum = red[0] + red[1] + red[2] + red[3];
  sq = red[4] + red[5] + red[6] + red[7];
  const float mean = sum * (1.f / 1024.f);
  const float var = sq * (1.f / 1024.f) - mean * mean;
  const float rstd = rsqrtf(var + 1e-5f);
#pragma unroll
  for (int i = 0; i < 4; ++i) {
    const int d = tid + i * 256;
    const float y = (x[i] - mean) * rstd * g[d] + bb[d];
    s[d] = y;
    outb[(size_t)row * D_ + d] = f2bf(y);
  }
}

// ---------------------------------------------------------------------------
// Host orchestration
// ---------------------------------------------------------------------------
static inline int cdiv(int a, int b) { return (a + b - 1) / b; }

extern "C" void kernel_launch(void* const* d_in, const int* in_sizes, int n_in,
                              void* d_out, int out_size, void* d_ws, size_t ws_size,
                              hipStream_t stream) {
  const float* x    = (const float*)d_in[0];
  const float* Wq   = (const float*)d_in[1];
  const float* Wk   = (const float*)d_in[2];
  const float* Wv   = (const float*)d_in[3];
  const float* Wpk  = (const float*)d_in[4];
  const float* bpk  = (const float*)d_in[5];
  const float* Wpv  = (const float*)d_in[6];
  const float* bpv  = (const float*)d_in[7];
  const float* g1   = (const float*)d_in[8];
  const float* b1ln = (const float*)d_in[9];
  const float* W1   = (const float*)d_in[10];
  const float* b1   = (const float*)d_in[11];
  const float* W2   = (const float*)d_in[12];
  const float* b2   = (const float*)d_in[13];
  const float* g2   = (const float*)d_in[14];
  const float* b2ln = (const float*)d_in[15];

  char* wsb = (char*)d_ws;
  // Workspace map (~176 MB):
  float* cosT = (float*)(wsb + 0);                //   256 KB
  float* sinT = (float*)(wsb + 262144);           //   256 KB
  float* srcf = (float*)(wsb + 524288);           // 32.77 MB fp32 residual
  u16* srcb   = (u16*)(wsb + 33292288);           // 16.38 MB bf16 mirror
  u16* QKVb   = (u16*)(wsb + 49676288);           // 49.15 MB [8000][3072]
  u16* Ttmp   = (u16*)(wsb + 98828288);           // 16.78 MB [8][1024][1024] transposed K or V
  u16* Km     = (u16*)(wsb + 115605504);          // 16.38 MB [8][1000][1024]
  u16* Vmt    = (u16*)(wsb + 131989504);          // 16.78 MB [8][1024 d][1024 keys]
  u16* wbuf   = (u16*)(wsb + 148766720);          // 27.07 MB layer weights
  u16* hB     = QKVb;  // [8000][4096] overlaps QKVb+Ttmp (both dead at FFN time)

  u16* wqB  = wbuf + 0;          // [3072][1024] fused q,k,v
  u16* wpkB = wbuf + 3145728;    // [1000][1000]
  u16* wpvB = wbuf + 4145728;
  u16* w1B  = wbuf + 5145728;    // [4096][1024]
  u16* w2B  = wbuf + 9340032;    // [1024][4096]

  float* yF = (float*)d_out;  // attention-out / FFN2-out scratch

  tab_kernel<<<250, 256, 0, stream>>>(cosT, sinT);
  hipMemcpyAsync(srcf, x, (size_t)BT_ * D_ * sizeof(float), hipMemcpyDeviceToDevice, stream);
  convert_kernel<<<cdiv(BT_ * D_, 1024), 256, 0, stream>>>(x, srcb, BT_ * D_);

  for (int l = 0; l < 4; ++l) {
    convert_kernel<<<cdiv(1048576, 1024), 256, 0, stream>>>(Wq + (size_t)l * 1048576, wqB, 1048576);
    convert_kernel<<<cdiv(1048576, 1024), 256, 0, stream>>>(Wk + (size_t)l * 1048576, wqB + 1048576, 1048576);
    convert_kernel<<<cdiv(1048576, 1024), 256, 0, stream>>>(Wv + (size_t)l * 1048576, wqB + 2097152, 1048576);
    convert_kernel<<<cdiv(1000000, 1024), 256, 0, stream>>>(Wpk + (size_t)l * 1000000, wpkB, 1000000);
    convert_kernel<<<cdiv(1000000, 1024), 256, 0, stream>>>(Wpv + (size_t)l * 1000000, wpvB, 1000000);
    convert_kernel<<<cdiv(4194304, 1024), 256, 0, stream>>>(W1 + (size_t)l * 4194304, w1B, 4194304);
    convert_kernel<<<cdiv(4194304, 1024), 256, 0, stream>>>(W2 + (size_t)l * 4194304, w2B, 4194304);

    // Fused QKV: (8000x3072) = srcb x [Wq;Wk;Wv]^T
    gemm_nt<0, false, true><<<dim3(24, 63, 1), 256, 0, stream>>>(
        srcb, wqB, QKVb, nullptr, BT_, 3072, 1024, 1024, 1024, 3072, 0, 0, 0);

    // K position-mix: transpose K slice -> Ttmp[b][d][t], then NT GEMM.
    transpose_kernel<<<dim3(16, 16, 8), 256, 0, stream>>>(QKVb, Ttmp, 1024);
    // Km[b][u][d] = sum_t Wpk[u,t] * Ttmp[b][d][t] + bpk[u]
    gemm_nt<1, false, true><<<dim3(8, 8, 8), 256, 0, stream>>>(
        wpkB, Ttmp, Km, bpk + (size_t)l * 1000, 1000, 1024, 1024,
        1000, 1024, 1024, 0L, 1048576L, 1024000L);

    // V position-mix (transposed output): Vmt[b][d][u] = sum_t Ttmp[b][d][t]*Wpv[u,t] + bpv[u]
    transpose_kernel<<<dim3(16, 16, 8), 256, 0, stream>>>(QKVb, Ttmp, 2048);
    gemm_nt<2, false, true><<<dim3(8, 8, 8), 256, 0, stream>>>(
        Ttmp, wpvB, Vmt, bpv + (size_t)l * 1000, 1024, 1000, 1024,
        1024, 1000, 1024, 1048576L, 0L, 1048576L);

    rope_kernel<<<16000, 256, 0, stream>>>(QKVb, 3072, cosT, sinT);  // Q
    rope_kernel<<<16000, 256, 0, stream>>>(Km, 1024, cosT, sinT);

    attn_kernel<<<dim3(8, 64), 256, 0, stream>>>(QKVb, 3072, Km, Vmt, yF);

    addln_kernel<<<BT_, 256, 0, stream>>>(srcf, yF, g1 + (size_t)l * 1024,
                                          b1ln + (size_t)l * 1024, srcb);

    // FFN1 (+bias+gelu) -> bf16 h
    gemm_nt<2, true, true><<<dim3(32, 63, 1), 256, 0, stream>>>(
        srcb, w1B, hB, b1 + (size_t)l * 4096, BT_, 4096, 1024, 1024, 1024, 4096, 0, 0, 0);
    // FFN2 (+bias) -> fp32 d_out
    gemm_nt<2, false, false><<<dim3(8, 63, 1), 256, 0, stream>>>(
        hB, w2B, d_out, b2 + (size_t)l * 1024, BT_, 1024, 4096, 4096, 4096, 1024, 0, 0, 0);

    addln_kernel<<<BT_, 256, 0, stream>>>(srcf, yF, g2 + (size_t)l * 1024,
                                          b2ln + (size_t)l * 1024, srcb);
  }

  hipMemcpyAsync(d_out, srcf, (size_t)BT_ * D_ * sizeof(float), hipMemcpyDeviceToDevice, stream);
}